// Round 8
// baseline (524.067 us; speedup 1.0000x reference)
//
#include <hip/hip_runtime.h>
#include <hip/hip_bf16.h>

// Problem constants
#define NB 2
#define NN 512
#define HH 128
#define DD 128
#define TT 8

// ws layout (bytes).
#define WPACK_OFF 0        // ushort[16*144*8] = 36864 B, bf16 [k/8][n][k%8]
#define C_OFF     36864    // float[2*512*128]  z@Wm1 + g@Wmg + (bm1+bm2+bme+bmg)
#define BROW_OFF  561152   // float[2*512*128]  z@Wm2
#define TC_OFF    1085440  // float[2*512*8]    z@Wt1 + g@Wtg + (bt1+bt2+bte+btg)
#define TB_OFF    1118208  // float[2*512*8]    z@Wt2
#define OC_OFF    1150976  // float[2*512*128]  z@Wo1 + bo1 + bo2
#define PART_OFF  1675264  // float[2*16*512*128] partial max (no C) per 32-sender chunk
#define ZF_OFF    10063872 // int[2*16*512]     1 if any sender in chunk has adj==0

#define OUT_TRI   131072   // float offset of tri_msgs in d_out

typedef float f32x4 __attribute__((ext_vector_type(4)));
typedef short s16x8 __attribute__((ext_vector_type(8)));

__device__ __forceinline__ unsigned short f2bf(float f) {
    union { float f; unsigned int u; } x; x.f = f;
    unsigned int u = x.u;
    unsigned int r = (u + 0x7FFFu + ((u >> 16) & 1u)) >> 16;  // RNE
    return (unsigned short)r;
}

// packed f32x2 -> bf16x2 (RNE). HW instr v_cvt_pk_bf16_f32 when available.
__device__ __forceinline__ unsigned cvt2bf(float a, float b) {
#if __has_builtin(__builtin_amdgcn_cvt_pk_bf16_f32)
    auto r = __builtin_amdgcn_cvt_pk_bf16_f32(a, b);
    return __builtin_bit_cast(unsigned, r);
#else
    return (unsigned)f2bf(a) | ((unsigned)f2bf(b) << 16);
#endif
}

// ---------------------------------------------------------------------------
// k0: precompute small projections (fp32) + pack bf16 weights for MFMA
// grid 513 x 256: blocks 0..511 handle 2 rows each; block 512 packs weights.
// ---------------------------------------------------------------------------
__global__ __launch_bounds__(256) void k0_precompute(
    const float* __restrict__ node, const float* __restrict__ hidden,
    const float* __restrict__ graph,
    const float* __restrict__ Wm1, const float* __restrict__ Wm2,
    const float* __restrict__ Wo1, const float* __restrict__ Wmg,
    const float* __restrict__ Wt1, const float* __restrict__ Wt2,
    const float* __restrict__ Wtg,
    const float* __restrict__ Wme, const float* __restrict__ Wte,
    const float* __restrict__ bm1, const float* __restrict__ bm2,
    const float* __restrict__ bme, const float* __restrict__ bmg,
    const float* __restrict__ bo1, const float* __restrict__ bo2,
    const float* __restrict__ bt1, const float* __restrict__ bt2,
    const float* __restrict__ bte, const float* __restrict__ btg,
    char* __restrict__ ws)
{
    const int bx = blockIdx.x, tid = threadIdx.x;
    if (bx == 512) {
        unsigned short* wp = (unsigned short*)(ws + WPACK_OFF);
        for (int idx = tid; idx < 16 * 144 * 8; idx += 256) {
            int j = idx & 7, tmp = idx >> 3;
            int n = tmp % 144, kq = tmp / 144;
            int k = kq * 8 + j;
            float v = 0.f;
            if (n < 128) v = Wme[k * 128 + n];
            else if (n < 136) v = Wte[k * 8 + (n - 128)];
            wp[idx] = f2bf(v);
        }
        return;
    }
    __shared__ float zs[2 * 260];
    const int row0 = bx * 2;       // flat row = b*512 + n
    const int b = row0 >> 9;
    #pragma unroll
    for (int e = 0; e < 2; e++) {
        int idx = e * 256 + tid;
        int rl = idx >> 8, col = idx & 255;
        float v = (col < 128) ? node[(row0 + rl) * 128 + col]
                              : hidden[(row0 + rl) * 128 + col - 128];
        zs[rl * 260 + col] = v;
    }
    __syncthreads();

    float* Cws = (float*)(ws + C_OFF);
    float* Bws = (float*)(ws + BROW_OFF);
    float* Ows = (float*)(ws + OC_OFF);
    float* TCw = (float*)(ws + TC_OFF);
    float* TBw = (float*)(ws + TB_OFF);

    const int d = tid & 127, half = tid >> 7;
    const int row = row0 + half;
    const float* z = zs + half * 260;
    float c = 0.f, q = 0.f, o = 0.f;
    #pragma unroll 8
    for (int k = 0; k < 256; k++) {
        float za = z[k];
        c = fmaf(za, Wm1[k * 128 + d], c);
        q = fmaf(za, Wm2[k * 128 + d], q);
        o = fmaf(za, Wo1[k * 128 + d], o);
    }
    float gm = 0.f;
    #pragma unroll 8
    for (int k = 0; k < 128; k++) gm = fmaf(graph[b * 128 + k], Wmg[k * 128 + d], gm);
    const float cb = gm + bm1[d] + bm2[d] + bme[d] + bmg[d];
    Cws[row * 128 + d] = c + cb;
    Bws[row * 128 + d] = q;
    Ows[row * 128 + d] = o + bo1[d] + bo2[d];

    if (tid < 32) {
        int rl = tid >> 4, t = (tid >> 1) & 7, which = tid & 1;
        const float* zr = zs + rl * 260;
        const float* W = which ? Wt2 : Wt1;
        float acc = 0.f;
        #pragma unroll 8
        for (int k = 0; k < 256; k++) acc = fmaf(zr[k], W[k * 8 + t], acc);
        int rg = row0 + rl;
        if (which == 0) {
            float gt = 0.f;
            #pragma unroll 8
            for (int k = 0; k < 128; k++) gt = fmaf(graph[b * 128 + k], Wtg[k * 8 + t], gt);
            TCw[rg * 8 + t] = acc + gt + bt1[t] + bt2[t] + bte[t] + btg[t];
        } else {
            TBw[rg * 8 + t] = acc;
        }
    }
}

// ---------------------------------------------------------------------------
// k2: fused edge GEMM + tri + masked max — BARRIER-FREE, NO LDS.
// Every wave consumes the FULL A tile (all K=128 features), so cooperative
// LDS staging only deduplicated the 4 waves' reads at the price of a
// full-block barrier (+ vmcnt drain) per sender — the r0/r1 DMA-ring attempt
// to keep loads in flight across that barrier was NEUTRAL (470->481 us),
// so the barrier either still drained (compiler-inserted waits, unobservable
// here) or wasn't the cost. This version removes the question: each lane
// loads its MFMA A-fragment directly from global (8x dwordx4; instruction
// pairs cover each 128-B row segment fully -> coalesced), 1-deep register
// prefetch of the next sender, zero inter-wave coupling. The 4x read
// amplification is absorbed by L1/L2 (~20 TB/s demand vs 34.5 TB/s L2
// ceiling; HBM traffic unchanged). ~12 independent waves/CU each with 8 KB
// of loads in flight >> 9 KB/CU Little's-law requirement -> HBM-saturating
// by TLP alone, nothing for the compiler to drain.
// grid (32 jt, 16 ic, 2 b) = 1024 blocks x 256 thr (4 waves).
// ---------------------------------------------------------------------------
__global__ __launch_bounds__(256, 3) void k2_main(
    const float* __restrict__ edge, const float* __restrict__ adj,
    char* __restrict__ ws, float* __restrict__ out)
{
    const int tid = threadIdx.x;
    const int jt = blockIdx.x, ic = blockIdx.y, b = blockIdx.z;
    const int j0 = jt * 16, i0 = ic * 32;

    const int lane = tid & 63, wave = tid >> 6;
    const int quad = lane >> 4, l15 = lane & 15;

    const float* Bws = (const float*)(ws + BROW_OFF);
    const float* TCw = (const float*)(ws + TC_OFF);
    const float* TBw = (const float*)(ws + TB_OFF);
    const s16x8* wp8 = (const s16x8*)(ws + WPACK_OFF);
    float* part = (float*)(ws + PART_OFF);
    int* Zws = (int*)(ws + ZF_OFF);

    // B fragments: 2 D tiles (cols (2*wave+ntl)*16+l15) + tri tile (cols 128+)
    s16x8 Bf[2][4], Bt[4];
    #pragma unroll
    for (int s = 0; s < 4; s++) {
        Bf[0][s] = wp8[(4 * s + quad) * 144 + (2 * wave) * 16 + l15];
        Bf[1][s] = wp8[(4 * s + quad) * 144 + (2 * wave + 1) * 16 + l15];
        Bt[s]    = wp8[(4 * s + quad) * 144 + 128 + l15];
    }

    const int jb = j0 + quad * 4;
    float TCf[4];
    #pragma unroll
    for (int r = 0; r < 4; r++)
        TCf[r] = (l15 < 8) ? TCw[(b * 512 + jb + r) * 8 + l15] : 0.f;

    // per-lane A source: row (j0+l15) of sender ig, cols quad*8 + s*32 + 0..7
    // (identical fragment mapping to the LDS version — verified passing).
    const float* gA = edge + ((size_t)(b * 512 + i0) * 512 + (j0 + l15)) * 128
                    + quad * 8;

    float Mx[2][4];
    #pragma unroll
    for (int ntl = 0; ntl < 2; ntl++)
        #pragma unroll
        for (int r = 0; r < 4; r++) Mx[ntl][r] = -INFINITY;
    int anyz[4] = {0, 0, 0, 0};

    const int c0 = (2 * wave) * 16 + l15, c1 = c0 + 16;

    // prologue: load sender 0's A fragments into registers
    float4 pf[8];
    #pragma unroll
    for (int s = 0; s < 4; s++) {
        pf[2 * s]     = *(const float4*)(gA + s * 32);
        pf[2 * s + 1] = *(const float4*)(gA + s * 32 + 4);
    }
    const float* gp = gA + 65536;   // next sender (stride 512*128 floats)

    for (int ii = 0; ii < 32; ii++) {
        const int ig = i0 + ii;
        const int rowb = b * 512 + ig;

        // 1. convert prefetched A to bf16 fragments (frees pf for next load)
        s16x8 af[4];
        #pragma unroll
        for (int s = 0; s < 4; s++) {
            union { s16x8 v; unsigned u[4]; } pk;
            pk.u[0] = cvt2bf(pf[2 * s].x, pf[2 * s].y);
            pk.u[1] = cvt2bf(pf[2 * s].z, pf[2 * s].w);
            pk.u[2] = cvt2bf(pf[2 * s + 1].x, pf[2 * s + 1].y);
            pk.u[3] = cvt2bf(pf[2 * s + 1].z, pf[2 * s + 1].w);
            af[s] = pk.v;
        }

        // 2. prefetch next sender's A (in flight across MFMA + epilogue)
        if (ii < 31) {
            #pragma unroll
            for (int s = 0; s < 4; s++) {
                pf[2 * s]     = *(const float4*)(gp + s * 32);
                pf[2 * s + 1] = *(const float4*)(gp + s * 32 + 4);
            }
            gp += 65536;
        }

        // 3. this sender's small operands
        const float4 adjv = *(const float4*)(adj + (size_t)rowb * 512 + jb);
        const float brw0 = Bws[rowb * 128 + c0];
        const float brw1 = Bws[rowb * 128 + c1];
        const float tb   = TBw[rowb * 8 + (l15 & 7)];

        // 4. MFMA: 2 D tiles always; tri tile when it's my turn
        f32x4 acc0 = (f32x4){0.f, 0.f, 0.f, 0.f};
        f32x4 acc1 = (f32x4){0.f, 0.f, 0.f, 0.f};
        #pragma unroll
        for (int s = 0; s < 4; s++) {
            acc0 = __builtin_amdgcn_mfma_f32_16x16x32_bf16(af[s], Bf[0][s], acc0, 0, 0, 0);
            acc1 = __builtin_amdgcn_mfma_f32_16x16x32_bf16(af[s], Bf[1][s], acc1, 0, 0, 0);
        }
        const int trimine = ((ii & 3) == wave);
        f32x4 acct = (f32x4){0.f, 0.f, 0.f, 0.f};
        if (trimine) {
            #pragma unroll
            for (int s = 0; s < 4; s++)
                acct = __builtin_amdgcn_mfma_f32_16x16x32_bf16(af[s], Bt[s], acct, 0, 0, 0);
        }

        // 5. tri relu-store on my turn
        if (trimine && l15 < 8) {
            float* tout = out + OUT_TRI + ((size_t)rowb * 512 + jb) * 8 + l15;
            #pragma unroll
            for (int r = 0; r < 4; r++)
                tout[r * 8] = fmaxf(acct[r] + TCf[r] + tb, 0.f);
        }

        // 6. masked-max epilogue (C deferred to k3)
        const float av[4] = {adjv.x, adjv.y, adjv.z, adjv.w};
        #pragma unroll
        for (int r = 0; r < 4; r++) {
            const int isz = (av[r] == 0.f);
            anyz[r] |= isz;
            Mx[0][r] = fmaxf(Mx[0][r], isz ? -INFINITY : (acc0[r] + brw0));
            Mx[1][r] = fmaxf(Mx[1][r], isz ? -INFINITY : (acc1[r] + brw1));
        }
    }

    // store per-chunk partial max — waves own disjoint columns, no reduce
    #pragma unroll
    for (int r = 0; r < 4; r++) {
        const size_t pb = ((size_t)(b * 16 + ic) * 512 + jb + r) * 128;
        part[pb + c0] = Mx[0][r];
        part[pb + c1] = Mx[1][r];
    }
    if (wave == 0 && l15 == 0) {
        #pragma unroll
        for (int r = 0; r < 4; r++)
            Zws[(b * 16 + ic) * 512 + jb + r] = anyz[r];
    }
}

// ---------------------------------------------------------------------------
// k3: msgs = max(max_ic partial + C, anyzero?0:-inf); ret = Oc + msgs @ Wo2
// ---------------------------------------------------------------------------
__global__ __launch_bounds__(128) void k3_final(
    const char* __restrict__ ws, const float* __restrict__ Wo2,
    float* __restrict__ out)
{
    __shared__ float ms[128];
    const int bj = blockIdx.x, d = threadIdx.x;
    const int b = bj >> 9, j = bj & 511;
    const float* part = (const float*)(ws + PART_OFF);
    const int* Zws = (const int*)(ws + ZF_OFF);
    const float* Cws = (const float*)(ws + C_OFF);
    const float* Ows = (const float*)(ws + OC_OFF);

    const int rj = b * 512 + j;
    float m = -INFINITY;
    int zf = 0;
    #pragma unroll
    for (int ic = 0; ic < 16; ic++) {
        m = fmaxf(m, part[((size_t)(b * 16 + ic) * 512 + j) * 128 + d]);
        zf |= Zws[(b * 16 + ic) * 512 + j];
    }
    float c = Cws[rj * 128 + d];
    float mm = fmaxf(m + c, zf ? 0.f : -INFINITY);
    ms[d] = mm;
    __syncthreads();
    float acc = Ows[rj * 128 + d];
    #pragma unroll 8
    for (int k = 0; k < 128; k++) acc = fmaf(ms[k], Wo2[k * 128 + d], acc);
    out[rj * 128 + d] = acc;
}

extern "C" void kernel_launch(void* const* d_in, const int* in_sizes, int n_in,
                              void* d_out, int out_size, void* d_ws, size_t ws_size,
                              hipStream_t stream) {
    const float* node   = (const float*)d_in[0];
    const float* edge   = (const float*)d_in[1];
    const float* graph  = (const float*)d_in[2];
    const float* adj    = (const float*)d_in[3];
    const float* hidden = (const float*)d_in[4];
    const float* Wm1 = (const float*)d_in[5];  const float* bm1 = (const float*)d_in[6];
    const float* Wm2 = (const float*)d_in[7];  const float* bm2 = (const float*)d_in[8];
    const float* Wme = (const float*)d_in[9];  const float* bme = (const float*)d_in[10];
    const float* Wmg = (const float*)d_in[11]; const float* bmg = (const float*)d_in[12];
    const float* Wo1 = (const float*)d_in[13]; const float* bo1 = (const float*)d_in[14];
    const float* Wo2 = (const float*)d_in[15]; const float* bo2 = (const float*)d_in[16];
    const float* Wt1 = (const float*)d_in[17]; const float* bt1 = (const float*)d_in[18];
    const float* Wt2 = (const float*)d_in[19]; const float* bt2 = (const float*)d_in[20];
    const float* Wte = (const float*)d_in[21]; const float* bte = (const float*)d_in[22];
    const float* Wtg = (const float*)d_in[23]; const float* btg = (const float*)d_in[24];
    float* out = (float*)d_out;
    char* ws = (char*)d_ws;

    k0_precompute<<<dim3(513), dim3(256), 0, stream>>>(
        node, hidden, graph, Wm1, Wm2, Wo1, Wmg, Wt1, Wt2, Wtg, Wme, Wte,
        bm1, bm2, bme, bmg, bo1, bo2, bt1, bt2, bte, btg, ws);
    k2_main<<<dim3(32, 16, 2), dim3(256), 0, stream>>>(edge, adj, ws, out);
    k3_final<<<dim3(1024), dim3(128), 0, stream>>>(ws, Wo2, out);
}

// Round 13
// 479.419 us; speedup vs baseline: 1.0931x; 1.0931x over previous
//
#include <hip/hip_runtime.h>
#include <hip/hip_bf16.h>

// Problem constants
#define NB 2
#define NN 512
#define HH 128
#define DD 128
#define TT 8

// ws layout (bytes).
#define WPACK_OFF 0        // ushort[16*144*8] = 36864 B, bf16 [k/8][n][k%8]
#define C_OFF     36864    // float[2*512*128]  z@Wm1 + g@Wmg + (bm1+bm2+bme+bmg)
#define BROW_OFF  561152   // float[2*512*128]  z@Wm2
#define TC_OFF    1085440  // float[2*512*8]    z@Wt1 + g@Wtg + (bt1+bt2+bte+btg)
#define TB_OFF    1118208  // float[2*512*8]    z@Wt2
#define OC_OFF    1150976  // float[2*512*128]  z@Wo1 + bo1 + bo2
#define PART_OFF  1675264  // float[2*16*512*128] partial max (no C) per 32-sender chunk
#define ZF_OFF    10063872 // int[2*16*512]     1 if any sender in chunk has adj==0
#define MASK_OFF  10129408 // u32[2*512*16]     bit k = adj[b][ic*32+k][j] != 0
                           // (ws_size >= 1 GiB: harness poison fills 1 GiB)

#define OUT_TRI   131072   // float offset of tri_msgs in d_out

#define AP 132             // LDS A-row stride in floats (128 + 4 pad)

typedef float f32x4 __attribute__((ext_vector_type(4)));
typedef short s16x8 __attribute__((ext_vector_type(8)));

__device__ __forceinline__ unsigned short f2bf(float f) {
    union { float f; unsigned int u; } x; x.f = f;
    unsigned int u = x.u;
    unsigned int r = (u + 0x7FFFu + ((u >> 16) & 1u)) >> 16;  // RNE
    return (unsigned short)r;
}

// packed f32x2 -> bf16x2 (RNE). HW instr v_cvt_pk_bf16_f32 when available.
__device__ __forceinline__ unsigned cvt2bf(float a, float b) {
#if __has_builtin(__builtin_amdgcn_cvt_pk_bf16_f32)
    auto r = __builtin_amdgcn_cvt_pk_bf16_f32(a, b);
    return __builtin_bit_cast(unsigned, r);
#else
    return (unsigned)f2bf(a) | ((unsigned)f2bf(b) << 16);
#endif
}

// ---------------------------------------------------------------------------
// k0: precompute small projections (fp32) + pack bf16 weights + adj bitmask.
// grid 577 x 256: blocks 0..511 handle 2 rows each; block 512 packs weights;
// blocks 513..576 build the adjacency bitmask (one u32 word per thread).
// ---------------------------------------------------------------------------
__global__ __launch_bounds__(256) void k0_precompute(
    const float* __restrict__ node, const float* __restrict__ hidden,
    const float* __restrict__ graph, const float* __restrict__ adj,
    const float* __restrict__ Wm1, const float* __restrict__ Wm2,
    const float* __restrict__ Wo1, const float* __restrict__ Wmg,
    const float* __restrict__ Wt1, const float* __restrict__ Wt2,
    const float* __restrict__ Wtg,
    const float* __restrict__ Wme, const float* __restrict__ Wte,
    const float* __restrict__ bm1, const float* __restrict__ bm2,
    const float* __restrict__ bme, const float* __restrict__ bmg,
    const float* __restrict__ bo1, const float* __restrict__ bo2,
    const float* __restrict__ bt1, const float* __restrict__ bt2,
    const float* __restrict__ bte, const float* __restrict__ btg,
    char* __restrict__ ws)
{
    const int bx = blockIdx.x, tid = threadIdx.x;
    if (bx == 512) {
        unsigned short* wp = (unsigned short*)(ws + WPACK_OFF);
        for (int idx = tid; idx < 16 * 144 * 8; idx += 256) {
            int j = idx & 7, tmp = idx >> 3;
            int n = tmp % 144, kq = tmp / 144;
            int k = kq * 8 + j;
            float v = 0.f;
            if (n < 128) v = Wme[k * 128 + n];
            else if (n < 136) v = Wte[k * 8 + (n - 128)];
            wp[idx] = f2bf(v);
        }
        return;
    }
    if (bx >= 513) {
        // word mi = (b*512 + j)*16 + ic ; bit k = adj[b][ic*32+k][j] != 0
        unsigned* M = (unsigned*)(ws + MASK_OFF);
        const int mi = (bx - 513) * 256 + tid;          // 0..16383
        const int b2 = mi >> 13, rem = mi & 8191;
        const int j = rem >> 4, icc = rem & 15;
        const float* ap = adj + ((size_t)(b2 * 512 + icc * 32) * 512) + j;
        unsigned m = 0;
        #pragma unroll
        for (int k = 0; k < 32; k++)
            m |= (ap[(size_t)k * 512] != 0.f ? 1u : 0u) << k;
        M[mi] = m;
        return;
    }
    __shared__ float zs[2 * 260];
    const int row0 = bx * 2;       // flat row = b*512 + n
    const int b = row0 >> 9;
    #pragma unroll
    for (int e = 0; e < 2; e++) {
        int idx = e * 256 + tid;
        int rl = idx >> 8, col = idx & 255;
        float v = (col < 128) ? node[(row0 + rl) * 128 + col]
                              : hidden[(row0 + rl) * 128 + col - 128];
        zs[rl * 260 + col] = v;
    }
    __syncthreads();

    float* Cws = (float*)(ws + C_OFF);
    float* Bws = (float*)(ws + BROW_OFF);
    float* Ows = (float*)(ws + OC_OFF);
    float* TCw = (float*)(ws + TC_OFF);
    float* TBw = (float*)(ws + TB_OFF);

    const int d = tid & 127, half = tid >> 7;
    const int row = row0 + half;
    const float* z = zs + half * 260;
    float c = 0.f, q = 0.f, o = 0.f;
    #pragma unroll 8
    for (int k = 0; k < 256; k++) {
        float za = z[k];
        c = fmaf(za, Wm1[k * 128 + d], c);
        q = fmaf(za, Wm2[k * 128 + d], q);
        o = fmaf(za, Wo1[k * 128 + d], o);
    }
    float gm = 0.f;
    #pragma unroll 8
    for (int k = 0; k < 128; k++) gm = fmaf(graph[b * 128 + k], Wmg[k * 128 + d], gm);
    const float cb = gm + bm1[d] + bm2[d] + bme[d] + bmg[d];
    Cws[row * 128 + d] = c + cb;
    Bws[row * 128 + d] = q;
    Ows[row * 128 + d] = o + bo1[d] + bo2[d];

    if (tid < 32) {
        int rl = tid >> 4, t = (tid >> 1) & 7, which = tid & 1;
        const float* zr = zs + rl * 260;
        const float* W = which ? Wt2 : Wt1;
        float acc = 0.f;
        #pragma unroll 8
        for (int k = 0; k < 256; k++) acc = fmaf(zr[k], W[k * 8 + t], acc);
        int rg = row0 + rl;
        if (which == 0) {
            float gt = 0.f;
            #pragma unroll 8
            for (int k = 0; k < 128; k++) gt = fmaf(graph[b * 128 + k], Wtg[k * 8 + t], gt);
            TCw[rg * 8 + t] = acc + gt + bt1[t] + bt2[t] + bte[t] + btg[t];
        } else {
            TBw[rg * 8 + t] = acc;
        }
    }
}

// ---------------------------------------------------------------------------
// k2: fused edge GEMM + tri + masked max.
// = the proven-best LDS double-buffer structure (470 us total), with the
// per-iteration SMALL VMEM loads hoisted out of the loop.
// Evidence (round-8, no-LDS variant counters): k2 is latency-bound — HBM 12%,
// MfmaUtil 4.5%, VALUBusy 20%, occupancy 25%. No pipe is near a ceiling; the
// cost is per-iteration memory dependency chains. Original loop had 6 VMEM
// ops/iter: 2 edge dwordx4 (real work) + adjv float4 + brw0 + brw1 + tb.
// This version: adj -> prepacked 32-bit sender masks (4 VGPRs, loaded once);
// Bws/TBw rows for this block's 32 senders -> LDS (17 KB, staged once in the
// prologue). Inner loop now has exactly 2 VMEM ops (edge) + 3 LDS reads.
// ROUND-10 FIX: the Bs staging covered only rows 0..7 (256 thr x 1 float4 =
// 1024 of 4096 floats); rows 8..31 were uninitialized LDS -> absmax 17.9.
// Now each thread stages 4 rows (e-loop), covering all 32.
// grid (32 jt, 16 ic, 2 b) = 1024 blocks x 256 thr (4 waves).
// ---------------------------------------------------------------------------
__global__ __launch_bounds__(256, 4) void k2_main(
    const float* __restrict__ edge, const float* __restrict__ adj,
    char* __restrict__ ws, float* __restrict__ out)
{
    __shared__ __align__(16) float As[2][16 * AP];   // 2 x 8448 B
    __shared__ __align__(16) float Bs[32 * 128];     // 16 KB: Bws rows i0..i0+31
    __shared__ __align__(16) float Ts[32 * 8];       // 1 KB: TBw rows i0..i0+31
    const int tid = threadIdx.x;
    const int jt = blockIdx.x, ic = blockIdx.y, b = blockIdx.z;
    const int j0 = jt * 16, i0 = ic * 32;

    const int lane = tid & 63, wave = tid >> 6;
    const int quad = lane >> 4, l15 = lane & 15;

    const float* Bws = (const float*)(ws + BROW_OFF);
    const float* TCw = (const float*)(ws + TC_OFF);
    const float* TBw = (const float*)(ws + TB_OFF);
    const s16x8* wp8 = (const s16x8*)(ws + WPACK_OFF);
    const unsigned* Mws = (const unsigned*)(ws + MASK_OFF);
    float* part = (float*)(ws + PART_OFF);
    int* Zws = (int*)(ws + ZF_OFF);

    // B fragments: 2 D tiles (cols (2*wave+ntl)*16+l15) + tri tile (cols 128+)
    s16x8 Bf[2][4], Bt[4];
    #pragma unroll
    for (int s = 0; s < 4; s++) {
        Bf[0][s] = wp8[(4 * s + quad) * 144 + (2 * wave) * 16 + l15];
        Bf[1][s] = wp8[(4 * s + quad) * 144 + (2 * wave + 1) * 16 + l15];
        Bt[s]    = wp8[(4 * s + quad) * 144 + 128 + l15];
    }

    const int jb = j0 + quad * 4;
    float TCf[4];
    #pragma unroll
    for (int r = 0; r < 4; r++)
        TCf[r] = (l15 < 8) ? TCw[(b * 512 + jb + r) * 8 + l15] : 0.f;

    // adjacency masks for my 4 output columns, all 32 senders (bit ii)
    unsigned mw[4];
    #pragma unroll
    for (int r = 0; r < 4; r++)
        mw[r] = Mws[(b * 512 + jb + r) * 16 + ic];

    // one-time LDS staging of per-sender row data (replaces per-iter VMEM).
    // 32 rows x 128 floats: each thread stages one float4 in each of 4 rows.
    {
        const int coff = (tid & 31) * 4;
        #pragma unroll
        for (int e = 0; e < 4; e++) {
            const int s = (tid >> 5) + e * 8;          // 0..31
            *(float4*)&Bs[s * 128 + coff] =
                *(const float4*)(Bws + (size_t)(b * 512 + i0 + s) * 128 + coff);
        }
        if (tid < 64) {
            const int s2 = tid >> 1, o2 = (tid & 1) * 4;
            *(float4*)&Ts[s2 * 8 + o2] =
                *(const float4*)(TBw + (size_t)(b * 512 + i0 + s2) * 8 + o2);
        }
    }

    // staging addressing: two float4 chunks per thread per sender
    const int f0 = tid, f1 = tid + 256;
    const int g0off = (f0 >> 5) * 128 + (f0 & 31) * 4;
    const int g1off = (f1 >> 5) * 128 + (f1 & 31) * 4;
    const int l0off = (f0 >> 5) * AP + (f0 & 31) * 4;
    const int l1off = (f1 >> 5) * AP + (f1 & 31) * 4;

    const size_t ebase = ((size_t)(b * 512 + i0) * 512 + j0) * 128;
    {   // prologue: sender i0 -> buf 0
        const float* nb = edge + ebase;
        *(float4*)&As[0][l0off] = *(const float4*)(nb + g0off);
        *(float4*)&As[0][l1off] = *(const float4*)(nb + g1off);
    }
    __syncthreads();

    float Mx[2][4];
    #pragma unroll
    for (int ntl = 0; ntl < 2; ntl++)
        #pragma unroll
        for (int r = 0; r < 4; r++) Mx[ntl][r] = -INFINITY;

    const int c0 = (2 * wave) * 16 + l15, c1 = c0 + 16;

    for (int ii = 0; ii < 32; ii++) {
        const int p = ii & 1, pn = p ^ 1;
        const int ig = i0 + ii;
        const int rowb = b * 512 + ig;

        // 1. issue next sender's A loads (the ONLY VMEM in the loop)
        float4 st0, st1;
        if (ii < 31) {
            const float* nb = edge + ebase + (size_t)(ii + 1) * 65536;
            st0 = *(const float4*)(nb + g0off);
            st1 = *(const float4*)(nb + g1off);
        }
        // 2. this sender's small operands — from LDS (staged in prologue)
        const float brw0 = Bs[ii * 128 + c0];
        const float brw1 = Bs[ii * 128 + c1];
        const float tb   = Ts[ii * 8 + (l15 & 7)];

        // 3. A fragments from LDS + cvt
        s16x8 af[4];
        const float* ap = &As[p][l15 * AP + quad * 8];
        #pragma unroll
        for (int s = 0; s < 4; s++) {
            float4 pv = *(const float4*)(ap + s * 32);
            float4 qv = *(const float4*)(ap + s * 32 + 4);
            union { s16x8 v; unsigned u[4]; } pk;
            pk.u[0] = cvt2bf(pv.x, pv.y);
            pk.u[1] = cvt2bf(pv.z, pv.w);
            pk.u[2] = cvt2bf(qv.x, qv.y);
            pk.u[3] = cvt2bf(qv.z, qv.w);
            af[s] = pk.v;
        }

        // 4. MFMA: 2 D tiles always; tri tile when it's my turn
        f32x4 acc0 = (f32x4){0.f, 0.f, 0.f, 0.f};
        f32x4 acc1 = (f32x4){0.f, 0.f, 0.f, 0.f};
        #pragma unroll
        for (int s = 0; s < 4; s++) {
            acc0 = __builtin_amdgcn_mfma_f32_16x16x32_bf16(af[s], Bf[0][s], acc0, 0, 0, 0);
            acc1 = __builtin_amdgcn_mfma_f32_16x16x32_bf16(af[s], Bf[1][s], acc1, 0, 0, 0);
        }
        const int trimine = ((ii & 3) == wave);
        f32x4 acct = (f32x4){0.f, 0.f, 0.f, 0.f};
        if (trimine) {
            #pragma unroll
            for (int s = 0; s < 4; s++)
                acct = __builtin_amdgcn_mfma_f32_16x16x32_bf16(af[s], Bt[s], acct, 0, 0, 0);
        }

        // 5. write next tile to the other LDS buffer (waits on st loads)
        if (ii < 31) {
            *(float4*)&As[pn][l0off] = st0;
            *(float4*)&As[pn][l1off] = st1;
        }

        // 6. masked-max epilogue via bitmask (no VMEM, no compares vs adj)
        #pragma unroll
        for (int r = 0; r < 4; r++) {
            const int ok = (mw[r] >> ii) & 1;
            Mx[0][r] = fmaxf(Mx[0][r], ok ? (acc0[r] + brw0) : -INFINITY);
            Mx[1][r] = fmaxf(Mx[1][r], ok ? (acc1[r] + brw1) : -INFINITY);
        }
        // 7. tri relu-store on my turn
        if (trimine && l15 < 8) {
            float* tout = out + OUT_TRI + ((size_t)rowb * 512 + jb) * 8 + l15;
            #pragma unroll
            for (int r = 0; r < 4; r++)
                tout[r * 8] = fmaxf(acct[r] + TCf[r] + tb, 0.f);
        }
        __syncthreads();
    }

    // store per-chunk partial max — waves own disjoint columns, no reduce
    #pragma unroll
    for (int r = 0; r < 4; r++) {
        const size_t pb = ((size_t)(b * 16 + ic) * 512 + jb + r) * 128;
        part[pb + c0] = Mx[0][r];
        part[pb + c1] = Mx[1][r];
    }
    if (wave == 0 && l15 == 0) {
        #pragma unroll
        for (int r = 0; r < 4; r++)
            Zws[(b * 16 + ic) * 512 + jb + r] = (mw[r] != 0xFFFFFFFFu) ? 1 : 0;
    }
}

// ---------------------------------------------------------------------------
// k3: msgs = max(max_ic partial + C, anyzero?0:-inf); ret = Oc + msgs @ Wo2
// ---------------------------------------------------------------------------
__global__ __launch_bounds__(128) void k3_final(
    const char* __restrict__ ws, const float* __restrict__ Wo2,
    float* __restrict__ out)
{
    __shared__ float ms[128];
    const int bj = blockIdx.x, d = threadIdx.x;
    const int b = bj >> 9, j = bj & 511;
    const float* part = (const float*)(ws + PART_OFF);
    const int* Zws = (const int*)(ws + ZF_OFF);
    const float* Cws = (const float*)(ws + C_OFF);
    const float* Ows = (const float*)(ws + OC_OFF);

    const int rj = b * 512 + j;
    float m = -INFINITY;
    int zf = 0;
    #pragma unroll
    for (int ic = 0; ic < 16; ic++) {
        m = fmaxf(m, part[((size_t)(b * 16 + ic) * 512 + j) * 128 + d]);
        zf |= Zws[(b * 16 + ic) * 512 + j];
    }
    float c = Cws[rj * 128 + d];
    float mm = fmaxf(m + c, zf ? 0.f : -INFINITY);
    ms[d] = mm;
    __syncthreads();
    float acc = Ows[rj * 128 + d];
    #pragma unroll 8
    for (int k = 0; k < 128; k++) acc = fmaf(ms[k], Wo2[k * 128 + d], acc);
    out[rj * 128 + d] = acc;
}

extern "C" void kernel_launch(void* const* d_in, const int* in_sizes, int n_in,
                              void* d_out, int out_size, void* d_ws, size_t ws_size,
                              hipStream_t stream) {
    const float* node   = (const float*)d_in[0];
    const float* edge   = (const float*)d_in[1];
    const float* graph  = (const float*)d_in[2];
    const float* adj    = (const float*)d_in[3];
    const float* hidden = (const float*)d_in[4];
    const float* Wm1 = (const float*)d_in[5];  const float* bm1 = (const float*)d_in[6];
    const float* Wm2 = (const float*)d_in[7];  const float* bm2 = (const float*)d_in[8];
    const float* Wme = (const float*)d_in[9];  const float* bme = (const float*)d_in[10];
    const float* Wmg = (const float*)d_in[11]; const float* bmg = (const float*)d_in[12];
    const float* Wo1 = (const float*)d_in[13]; const float* bo1 = (const float*)d_in[14];
    const float* Wo2 = (const float*)d_in[15]; const float* bo2 = (const float*)d_in[16];
    const float* Wt1 = (const float*)d_in[17]; const float* bt1 = (const float*)d_in[18];
    const float* Wt2 = (const float*)d_in[19]; const float* bt2 = (const float*)d_in[20];
    const float* Wte = (const float*)d_in[21]; const float* bte = (const float*)d_in[22];
    const float* Wtg = (const float*)d_in[23]; const float* btg = (const float*)d_in[24];
    float* out = (float*)d_out;
    char* ws = (char*)d_ws;

    k0_precompute<<<dim3(577), dim3(256), 0, stream>>>(
        node, hidden, graph, adj, Wm1, Wm2, Wo1, Wmg, Wt1, Wt2, Wtg, Wme, Wte,
        bm1, bm2, bme, bmg, bo1, bo2, bt1, bt2, bte, btg, ws);
    k2_main<<<dim3(32, 16, 2), dim3(256), 0, stream>>>(edge, adj, ws, out);
    k3_final<<<dim3(1024), dim3(128), 0, stream>>>(ws, Wo2, out);
}